// Round 9
// baseline (103.838 us; speedup 1.0000x reference)
//
#include <hip/hip_runtime.h>
#include <hip/hip_bf16.h>

#define B_ 32
#define D_ 512
#define N_ 1024
#define M_ 1024
#define BM 128
#define BK 64
#define NSTEP (D_ / BK)   // 8

typedef __attribute__((ext_vector_type(8))) short bf16x8;
typedef __attribute__((ext_vector_type(4))) float f32x4;
typedef __attribute__((ext_vector_type(4))) int   i32x4;
typedef unsigned short ushort_t;

__device__ __forceinline__ unsigned map_f(float f) {
    unsigned b = __float_as_uint(f);
    return (b & 0x80000000u) ? ~b : (b | 0x80000000u);
}

// ============================================================================
// Fused fp32->bf16 GEMM-max, single-buffered LDS (33KB -> 4 blocks/CU).
// LDS tile TRANSPOSED [j=128][k=64] bf16, row 128B = 8 granules of 16B.
//   byte(j,k) = j*128 + 16*((k>>3) ^ (j&7) ^ ((j>>3)&7)) + 2*(k&7)
// Writes: reg-staged cvt + 8x ds_write_b64/thread  (2-way bank alias = free).
// Reads : plain ds_read_b128 fragments (conflict-free, R2-verified pattern).
// ============================================================================
struct __align__(16) GSmem {
    ushort_t As[BM * BK];   // 16 KB
    ushort_t Bs[BM * BK];   // 16 KB
    float red[4];
};

// Load this thread's 4 rows x 8 cols fp32 slice of a [64][128] tile.
// krb = wave*16 + (lane>>4)*4 ; gr = lane&15. 16 lanes cover a full 512B row.
__device__ __forceinline__ void load_tile(const float* __restrict__ p, int k0,
                                          int krb, int gr, float4* fl) {
    #pragma unroll
    for (int it = 0; it < 4; ++it) {
        const float* q = p + (size_t)(k0 + krb + it) * N_ + gr * 8;
        fl[2 * it]     = *reinterpret_cast<const float4*>(q);
        fl[2 * it + 1] = *reinterpret_cast<const float4*>(q + 4);
    }
}

// Convert + write transposed: per thread 8 j-columns, 4 k's each (8B words).
__device__ __forceinline__ void flush_tile_T(char* lds, int krb, int gr, const float4* fl) {
    const int q    = (krb >> 3) & 7;
    const int koff = 2 * (krb & 7);
    const int g7   = gr & 7;
    #pragma unroll
    for (int jl = 0; jl < 8; ++jl) {
        const int hi = (jl >> 2) & 1, ji = jl & 3;
        const float* r0 = reinterpret_cast<const float*>(&fl[hi]);
        const float* r1 = reinterpret_cast<const float*>(&fl[2 + hi]);
        const float* r2 = reinterpret_cast<const float*>(&fl[4 + hi]);
        const float* r3 = reinterpret_cast<const float*>(&fl[6 + hi]);
        __hip_bfloat162 h0 = __float22bfloat162_rn(make_float2(r0[ji], r1[ji]));
        __hip_bfloat162 h1 = __float22bfloat162_rn(make_float2(r2[ji], r3[ji]));
        uint2 v = make_uint2(*reinterpret_cast<const unsigned*>(&h0),
                             *reinterpret_cast<const unsigned*>(&h1));
        const int j = gr * 8 + jl;
        *reinterpret_cast<uint2*>(lds + j * 128 + 16 * (q ^ jl ^ g7) + koff) = v;
    }
}

__global__ __launch_bounds__(256, 3)
void fused_gemm_max_kernel(const float* __restrict__ e1, const float* __restrict__ e2,
                           float* __restrict__ out) {
    __shared__ GSmem sm;
    const int wg  = blockIdx.x;
    const int swz = (wg & 7) * 256 + (wg >> 3);   // XCD swizzle (2048 % 8 == 0)
    const int b    = swz >> 6;
    const int tile = swz & 63;
    const int tn = (tile >> 3) * BM;
    const int tc = (tile & 7) * BM;

    const int t    = threadIdx.x;
    const int lane = t & 63;
    const int wave = t >> 6;
    const int wr   = (wave >> 1) * 64;   // A j-quadrant
    const int wc   = (wave & 1) * 64;    // B j-quadrant
    const int l15  = lane & 15;
    const int l4   = lane >> 4;

    // staging geometry
    const int krb = wave * 16 + l4 * 4;
    const int gr  = l15;

    // fragment read geometry: addr = j*128 + 16*((4*kk+l4) ^ cswz)
    int jA[4], jB[4], cswzA[4], cswzB[4];
    #pragma unroll
    for (int m = 0; m < 4; ++m) {
        jA[m] = wr + m * 16 + l15;
        cswzA[m] = (l15 & 7) ^ ((jA[m] >> 3) & 7);
        jB[m] = wc + m * 16 + l15;
        cswzB[m] = (l15 & 7) ^ ((jB[m] >> 3) & 7);
    }

    const float* Ap = e1 + (size_t)b * D_ * N_ + tn;
    const float* Bp = e2 + (size_t)b * D_ * M_ + tc;

    f32x4 acc[4][4] = {};
    float4 flA[8], flB[8];

    load_tile(Ap, 0, krb, gr, flA);
    load_tile(Bp, 0, krb, gr, flB);

    #pragma unroll 1
    for (int ks = 0; ks < NSTEP; ++ks) {
        flush_tile_T((char*)sm.As, krb, gr, flA);
        flush_tile_T((char*)sm.Bs, krb, gr, flB);
        if (ks < NSTEP - 1) {   // prefetch next tile into regs; lands during compute
            load_tile(Ap, (ks + 1) * BK, krb, gr, flA);
            load_tile(Bp, (ks + 1) * BK, krb, gr, flB);
        }
        asm volatile("s_waitcnt lgkmcnt(0)" ::: "memory");  // ds_writes visible; no vmcnt drain
        __builtin_amdgcn_s_barrier();

        #pragma unroll
        for (int kk = 0; kk < 2; ++kk) {
            const int q = 4 * kk + l4;
            bf16x8 af[4], bf[4];
            #pragma unroll
            for (int m = 0; m < 4; ++m)
                af[m] = *reinterpret_cast<const bf16x8*>(
                    (const char*)sm.As + jA[m] * 128 + 16 * (q ^ cswzA[m]));
            #pragma unroll
            for (int n = 0; n < 4; ++n)
                bf[n] = *reinterpret_cast<const bf16x8*>(
                    (const char*)sm.Bs + jB[n] * 128 + 16 * (q ^ cswzB[n]));
            __builtin_amdgcn_s_setprio(1);
            #pragma unroll
            for (int m = 0; m < 4; ++m)
                #pragma unroll
                for (int n = 0; n < 4; ++n)
                    acc[m][n] = __builtin_amdgcn_mfma_f32_16x16x32_bf16(
                        af[m], bf[n], acc[m][n], 0, 0, 0);
            __builtin_amdgcn_s_setprio(0);
        }
        // all waves done reading LDS before next flush overwrites it
        asm volatile("" ::: "memory");
        __builtin_amdgcn_s_barrier();
    }

    // Max over this thread's 64 accumulator values.
    float tmax = acc[0][0][0];
    #pragma unroll
    for (int m = 0; m < 4; ++m)
        #pragma unroll
        for (int n = 0; n < 4; ++n)
            #pragma unroll
            for (int i = 0; i < 4; ++i)
                tmax = fmaxf(tmax, acc[m][n][i]);
    #pragma unroll
    for (int off2 = 32; off2; off2 >>= 1)
        tmax = fmaxf(tmax, __shfl_xor(tmax, off2));
    if (lane == 0) sm.red[wave] = tmax;
    __syncthreads();
    if (t == 0) {
        float m4 = fmaxf(fmaxf(sm.red[0], sm.red[1]), fmaxf(sm.red[2], sm.red[3]));
        atomicMax(reinterpret_cast<unsigned*>(out) + b, map_f(m4));
    }
}

__global__ void finalize_kernel(float* out) {
    const int i = threadIdx.x;
    unsigned u = reinterpret_cast<unsigned*>(out)[i];
    out[i] = __uint_as_float((u & 0x80000000u) ? (u ^ 0x80000000u) : ~u);
}

extern "C" void kernel_launch(void* const* d_in, const int* in_sizes, int n_in,
                              void* d_out, int out_size, void* d_ws, size_t ws_size,
                              hipStream_t stream) {
    const float* e1 = (const float*)d_in[0];
    const float* e2 = (const float*)d_in[1];
    float* out = (float*)d_out;

    hipMemsetAsync(d_out, 0, B_ * sizeof(float), stream);  // 0 == -inf under map_f

    fused_gemm_max_kernel<<<dim3(2048), 256, 0, stream>>>(e1, e2, out);
    finalize_kernel<<<1, B_, 0, stream>>>(out);
}